// Round 1
// baseline (946.128 us; speedup 1.0000x reference)
//
#include <hip/hip_runtime.h>

// Viterbi CRF decode: potentials [B,T,C] f32, transitions [C,C] f32 -> one-hot [B,T,C] f32
// B=256, T=1024, C=128.

constexpr int NB = 256;
constexpr int NT = 1024;
constexpr int NC = 128;
constexpr int NTHREADS = 512;

// LDS layout (dynamic):
//   bp     : (NT-1)*NC uint8 = 130944 B   (backpointers, all timesteps)
//   alpha  : 2 * 432 floats   = 3456 B    (double-buffered, padded: chunk s at s*132..s*132+31)
//   tags   : NT ints          = 4096 B
constexpr int BP_BYTES    = (NT - 1) * NC;             // 130944
constexpr int ALPHA_FL    = 432;                       // padded floats per buffer (4 chunks * 132)
constexpr int ALPHA_OFF   = BP_BYTES;                  // 16B aligned (130944 % 16 == 0)
constexpr int TAGS_OFF    = ALPHA_OFF + 2 * ALPHA_FL * 4;
constexpr int SMEM_BYTES  = TAGS_OFF + NT * 4;         // 138496 B < 160 KiB

__device__ __forceinline__ int alpha_idx(int c) {
  return (c >> 5) * 132 + (c & 31);   // padded so the 4 s-chunks never share banks
}

__global__ __launch_bounds__(NTHREADS, 1)
void crf_viterbi_kernel(const float* __restrict__ pot,
                        const float* __restrict__ trans,
                        float* __restrict__ out) {
  extern __shared__ char smem[];
  unsigned char* bp_lds = (unsigned char*)smem;
  float* alpha = (float*)(smem + ALPHA_OFF);
  int* tags = (int*)(smem + TAGS_OFF);

  const int tid = threadIdx.x;
  const int b = blockIdx.x;
  const int c = tid >> 2;   // 0..127 : output state this thread computes
  const int s = tid & 3;    // 0..3   : p-chunk (p = s*32 .. s*32+31)
  const float* potb = pot + (size_t)b * NT * NC;

  // Transition column into registers (time-invariant): tr[k] = trans[(s*32+k)][c]
  float tr[32];
  #pragma unroll
  for (int k = 0; k < 32; ++k) tr[k] = trans[(s * 32 + k) * NC + c];

  // alpha_0 = pot[:,0,:]
  if (s == 0) {
    alpha[alpha_idx(c)] = potb[c];
  }

  // Register prefetch of pot rows: thread (c,s) holds pot[t0+s][c] for its 4-step group.
  float pot_cur  = potb[(1 + s) * NC + c];
  float pot_next = potb[(5 + s) * NC + c];

  // Raw barrier: wait LDS writes only; do NOT drain vmcnt (keeps pot prefetch in flight).
  asm volatile("s_waitcnt lgkmcnt(0)\n\ts_barrier" ::: "memory");

  int cur = 0;

  auto step = [&](int t, int phi) {
    const float4* af4 = (const float4*)(alpha + cur * ALPHA_FL);
    float m = -__builtin_inff();
    int bi = 0;
    #pragma unroll
    for (int k4 = 0; k4 < 8; ++k4) {
      float4 a = af4[s * 33 + k4];          // broadcast LDS read, conflict-free banks
      float v0 = a.x + tr[k4 * 4 + 0];
      float v1 = a.y + tr[k4 * 4 + 1];
      float v2 = a.z + tr[k4 * 4 + 2];
      float v3 = a.w + tr[k4 * 4 + 3];
      if (v0 > m) { m = v0; bi = k4 * 4 + 0; }   // strict '>' keeps FIRST max (lowest p)
      if (v1 > m) { m = v1; bi = k4 * 4 + 1; }
      if (v2 > m) { m = v2; bi = k4 * 4 + 2; }
      if (v3 > m) { m = v3; bi = k4 * 4 + 3; }
    }
    int p = s * 32 + bi;
    // combine the 4 partials for this c (lanes differ only in s): butterfly in the quad
    #pragma unroll
    for (int d = 1; d <= 2; d <<= 1) {
      float mo = __shfl_xor(m, d);
      int   po = __shfl_xor(p, d);
      if (mo > m || (mo == m && po < p)) { m = mo; p = po; }  // tie -> lowest p
    }
    float pb = __shfl(pot_cur, phi, 4);     // broadcast pot[t][c] from the phase lane
    float na = m + pb;
    if (s == 0) {
      alpha[(cur ^ 1) * ALPHA_FL + alpha_idx(c)] = na;
      bp_lds[(t - 1) * NC + c] = (unsigned char)p;
    }
    asm volatile("s_waitcnt lgkmcnt(0)\n\ts_barrier" ::: "memory");
    cur ^= 1;
  };

  // 1023 steps = 255 groups of 4 + 3 tail steps
  for (int g = 0; g < 255; ++g) {
    int t0 = 1 + 4 * g;
    step(t0 + 0, 0);
    step(t0 + 1, 1);
    step(t0 + 2, 2);
    step(t0 + 3, 3);
    pot_cur = pot_next;                       // waits vmcnt at first use, issued ~8 steps ago
    int r = 1 + 4 * (g + 2) + s;
    if (r > NT - 1) r = NT - 1;               // clamp (tail rows unused but must be in-bounds)
    pot_next = potb[r * NC + c];
  }
  step(1021, 0);
  step(1022, 1);
  step(1023, 2);

  // Final argmax over alpha_T (wave 0), then serial backpointer chase in LDS (thread 0)
  if (tid < 64) {
    float v0 = alpha[cur * ALPHA_FL + alpha_idx(tid)];
    float v1 = alpha[cur * ALPHA_FL + alpha_idx(tid + 64)];
    float mv = v0; int mc = tid;
    if (v1 > mv) { mv = v1; mc = tid + 64; }
    #pragma unroll
    for (int d = 32; d >= 1; d >>= 1) {
      float vo = __shfl_xor(mv, d);
      int   co = __shfl_xor(mc, d);
      if (vo > mv || (vo == mv && co < mc)) { mv = vo; mc = co; }
    }
    if (tid == 0) {
      int tag = mc;
      tags[NT - 1] = tag;
      for (int i = NT - 2; i >= 0; --i) {
        tag = bp_lds[i * NC + tag];
        tags[i] = tag;
      }
    }
  }
  __syncthreads();

  // One-hot fill: 4096 tasks of 128 contiguous bytes... (32 floats each), coalesced
  float* outb = out + (size_t)b * NT * NC;
  #pragma unroll
  for (int it = 0; it < 8; ++it) {
    int task = it * NTHREADS + tid;
    int row = task >> 2, q = task & 3;
    int tag = tags[row];
    float4* dst = (float4*)(outb + row * NC + q * 32);
    #pragma unroll
    for (int k4 = 0; k4 < 8; ++k4) {
      int cb = q * 32 + k4 * 4;
      float4 v;
      v.x = (cb + 0 == tag) ? 1.0f : 0.0f;
      v.y = (cb + 1 == tag) ? 1.0f : 0.0f;
      v.z = (cb + 2 == tag) ? 1.0f : 0.0f;
      v.w = (cb + 3 == tag) ? 1.0f : 0.0f;
      dst[k4] = v;
    }
  }
}

extern "C" void kernel_launch(void* const* d_in, const int* in_sizes, int n_in,
                              void* d_out, int out_size, void* d_ws, size_t ws_size,
                              hipStream_t stream) {
  const float* pot   = (const float*)d_in[0];
  const float* trans = (const float*)d_in[1];
  float* out = (float*)d_out;

  // >64 KiB dynamic LDS needs the attribute (idempotent; host-side, capture-safe)
  hipFuncSetAttribute((const void*)crf_viterbi_kernel,
                      hipFuncAttributeMaxDynamicSharedMemorySize, SMEM_BYTES);

  crf_viterbi_kernel<<<NB, NTHREADS, SMEM_BYTES, stream>>>(pot, trans, out);
}

// Round 2
// 555.153 us; speedup vs baseline: 1.7043x; 1.7043x over previous
//
#include <hip/hip_runtime.h>

// Viterbi CRF decode: potentials [B,T,C] f32, transitions [C,C] f32 -> one-hot [B,T,C] f32
// B=256, T=1024, C=128.
//
// Two-kernel design:
//   crf_fwd : max-only DP (no argmax). Streams alpha[t] rows into d_out (same
//             shape as the final output) as scratch.
//   crf_bwd : recomputes backpointers on the fly from stored alphas (exact fp32
//             replay -> identical argmax, first-occurrence tie-break), chases the
//             Viterbi path, and overwrites d_out with the one-hot decode.

constexpr int NB = 256;
constexpr int NT = 1024;
constexpr int NC = 128;

// ---------------- shared helpers ----------------

template <int CTRL>
__device__ __forceinline__ float fmax_dpp(float v) {
  int x = __builtin_amdgcn_update_dpp(__float_as_int(v), __float_as_int(v),
                                      CTRL, 0xF, 0xF, false);
  return fmaxf(v, __int_as_float(x));
}

__device__ __forceinline__ float fmax_swz_xor4(float v) {
  // ds_swizzle BitMode: xor=4, or=0, and=0x1F  -> lane ^ 4
  int x = __builtin_amdgcn_ds_swizzle(__float_as_int(v), 0x101F);
  return fmaxf(v, __int_as_float(x));
}

// full-wave (64-lane) max reduce, result valid after readlane(63)
__device__ __forceinline__ float wave_max_to_lane63(float m) {
  m = fmax_dpp<0x111>(m);  // row_shr:1
  m = fmax_dpp<0x112>(m);  // row_shr:2
  m = fmax_dpp<0x114>(m);  // row_shr:4
  m = fmax_dpp<0x118>(m);  // row_shr:8  -> lane15 of each row has row max
  m = fmax_dpp<0x142>(m);  // row_bcast:15
  m = fmax_dpp<0x143>(m);  // row_bcast:31 -> lane63 has full max
  return m;
}

// ---------------- forward ----------------
// 1024 threads: c = tid>>3 (output state), s = tid&7 (16-wide p chunk).
// alpha double-buffered in LDS, padded 32->36 per chunk so the 8 s-chunks'
// float4 reads cover all 32 banks (conflict-free broadcast).

constexpr int AROW = 144;  // 4 chunks * 36 floats

__device__ __forceinline__ int aidx(int p) { return (p >> 5) * 36 + (p & 31); }

__global__ __launch_bounds__(1024)
void crf_fwd(const float* __restrict__ pot, const float* __restrict__ trans,
             float* __restrict__ out) {
  __shared__ __align__(16) float alpha[2 * AROW];

  const int tid = threadIdx.x;
  const int b = blockIdx.x;
  const int c = tid >> 3;
  const int s = tid & 7;
  const float* potb = pot + (size_t)b * NT * NC;
  float* outb = out + (size_t)b * NT * NC;

  // time-invariant transition column slice: tr[k] = trans[s*16+k][c]
  float tr[16];
  #pragma unroll
  for (int k = 0; k < 16; ++k) tr[k] = trans[(s * 16 + k) * NC + c];

  float pc[8], pn[8];  // pot row prefetch (only s==0 lanes use them)
  if (s == 0) {
    float a0 = potb[c];          // alpha_0 = pot[:,0,:]
    alpha[aidx(c)] = a0;
    outb[c] = a0;                // stash alpha row 0
    #pragma unroll
    for (int j = 0; j < 8; ++j) pc[j] = potb[(1 + j) * NC + c];
  }
  // LDS-only barrier: keep global loads/stores in flight
  asm volatile("s_waitcnt lgkmcnt(0)\n\ts_barrier" ::: "memory");

  int cur = 0;
  const int fbase = ((s >> 1) * 36 + (s & 1) * 16) >> 2;  // float4 index, 16B-aligned

  auto STEP = [&](int t, int j) {
    const float4* af = (const float4*)(alpha + cur * AROW);
    float4 a0 = af[fbase + 0];
    float4 a1 = af[fbase + 1];
    float4 a2 = af[fbase + 2];
    float4 a3 = af[fbase + 3];
    float v[16];
    v[0]  = a0.x + tr[0];  v[1]  = a0.y + tr[1];
    v[2]  = a0.z + tr[2];  v[3]  = a0.w + tr[3];
    v[4]  = a1.x + tr[4];  v[5]  = a1.y + tr[5];
    v[6]  = a1.z + tr[6];  v[7]  = a1.w + tr[7];
    v[8]  = a2.x + tr[8];  v[9]  = a2.y + tr[9];
    v[10] = a2.z + tr[10]; v[11] = a2.w + tr[11];
    v[12] = a3.x + tr[12]; v[13] = a3.y + tr[13];
    v[14] = a3.z + tr[14]; v[15] = a3.w + tr[15];
    #pragma unroll
    for (int off = 8; off >= 1; off >>= 1) {
      #pragma unroll
      for (int k = 0; k < off; ++k) v[k] = fmaxf(v[k], v[k + off]);
    }
    float m = v[0];
    m = fmax_dpp<0xB1>(m);   // quad_perm (1,0,3,2): xor 1
    m = fmax_dpp<0x4E>(m);   // quad_perm (2,3,0,1): xor 2
    m = fmax_swz_xor4(m);    // xor 4 -> all 8 s-lanes hold group max
    if (s == 0) {
      float na = m + pc[j];
      alpha[(cur ^ 1) * AROW + aidx(c)] = na;
      outb[t * NC + c] = na;           // stash alpha row t (fire-and-forget)
    }
    asm volatile("s_waitcnt lgkmcnt(0)\n\ts_barrier" ::: "memory");
    cur ^= 1;
  };

  for (int g = 0; g < 127; ++g) {
    if (s == 0) {  // prefetch next group's pot rows (one group = 8 steps ahead)
      #pragma unroll
      for (int j = 0; j < 8; ++j) {
        int r = 9 + 8 * g + j;
        if (r > NT - 1) r = NT - 1;
        pn[j] = potb[r * NC + c];
      }
    }
    const int t0 = 1 + 8 * g;
    STEP(t0 + 0, 0); STEP(t0 + 1, 1); STEP(t0 + 2, 2); STEP(t0 + 3, 3);
    STEP(t0 + 4, 4); STEP(t0 + 5, 5); STEP(t0 + 6, 6); STEP(t0 + 7, 7);
    #pragma unroll
    for (int j = 0; j < 8; ++j) pc[j] = pn[j];
  }
  // tail: t = 1017..1023
  STEP(1017, 0); STEP(1018, 1); STEP(1019, 2); STEP(1020, 3);
  STEP(1021, 4); STEP(1022, 5); STEP(1023, 6);
}

// ---------------- backward ----------------
// 256 threads: all 4 waves transpose trans into LDS, then wave 0 chases the
// path. Lane l owns states p = l and p = 64+l. Alpha rows register-prefetched
// 8 deep (independent of the serial tag chain). One-hot row t overwrites the
// already-consumed alpha row t in place.

__global__ __launch_bounds__(256)
void crf_bwd(const float* __restrict__ trans, float* __restrict__ out) {
  extern __shared__ float tT[];  // [NC][NC] : tT[c][p] = trans[p][c]
  const int tid = threadIdx.x;
  const int b = blockIdx.x;
  float* outb = out + (size_t)b * NT * NC;

  {
    const int r = tid >> 1;   // source row p
    const int h = tid & 1;    // which half of the row
    const float4* src = (const float4*)(trans + r * NC + h * 64);
    #pragma unroll
    for (int j = 0; j < 16; ++j) {
      float4 q = src[j];
      int cb = h * 64 + 4 * j;
      tT[(cb + 0) * NC + r] = q.x;   // bank = r%32: conflict-free across lanes
      tT[(cb + 1) * NC + r] = q.y;
      tT[(cb + 2) * NC + r] = q.z;
      tT[(cb + 3) * NC + r] = q.w;
    }
  }
  __syncthreads();
  if (tid >= 64) return;
  const int l = tid;

  // last_tag = first argmax of alpha[T-1]
  float zlo = outb[(NT - 1) * NC + l];
  float zhi = outb[(NT - 1) * NC + 64 + l];
  float m0 = wave_max_to_lane63(fmaxf(zlo, zhi));
  float M0 = __int_as_float(__builtin_amdgcn_readlane(__float_as_int(m0), 63));
  unsigned long long bl = __ballot(zlo == M0);
  unsigned long long bh = __ballot(zhi == M0);
  int tag = bl ? (__ffsll((long long)bl) - 1)
               : (64 + __ffsll((long long)bh) - 1);

  // prefetch alpha rows 1022..1015
  float clo[8], chi[8], nlo[8], nhi[8];
  #pragma unroll
  for (int j = 0; j < 8; ++j) {
    clo[j] = outb[(NT - 2 - j) * NC + l];
    chi[j] = outb[(NT - 2 - j) * NC + 64 + l];
  }

  for (int g = 0; g < 128; ++g) {
    #pragma unroll
    for (int j = 0; j < 8; ++j) {      // prefetch group g+1 (rows 1014-8g-j)
      int r = NT - 10 - 8 * g - j;
      if (r < 0) r = 0;
      nlo[j] = outb[r * NC + l];
      nhi[j] = outb[r * NC + 64 + l];
    }
    #pragma unroll
    for (int j = 0; j < 8; ++j) {
      int t = NT - 1 - 8 * g - j;
      if (t >= 1) {
        // one-hot for row t (alpha[t] already consumed last iteration)
        outb[t * NC + l]      = (l == tag) ? 1.0f : 0.0f;
        outb[t * NC + 64 + l] = (64 + l == tag) ? 1.0f : 0.0f;
        // bp: first argmax_p( alpha[t-1][p] + trans[p][tag] )
        float lo = clo[j] + tT[tag * NC + l];
        float hi = chi[j] + tT[tag * NC + 64 + l];
        float m = wave_max_to_lane63(fmaxf(lo, hi));
        float M = __int_as_float(__builtin_amdgcn_readlane(__float_as_int(m), 63));
        unsigned long long el = __ballot(lo == M);
        unsigned long long eh = __ballot(hi == M);
        tag = el ? (__ffsll((long long)el) - 1)
                 : (64 + __ffsll((long long)eh) - 1);
      }
    }
    #pragma unroll
    for (int j = 0; j < 8; ++j) { clo[j] = nlo[j]; chi[j] = nhi[j]; }
  }
  outb[l]      = (l == tag) ? 1.0f : 0.0f;
  outb[64 + l] = (64 + l == tag) ? 1.0f : 0.0f;
}

// ---------------- launch ----------------

extern "C" void kernel_launch(void* const* d_in, const int* in_sizes, int n_in,
                              void* d_out, int out_size, void* d_ws, size_t ws_size,
                              hipStream_t stream) {
  const float* pot   = (const float*)d_in[0];
  const float* trans = (const float*)d_in[1];
  float* out = (float*)d_out;

  hipFuncSetAttribute((const void*)crf_bwd,
                      hipFuncAttributeMaxDynamicSharedMemorySize, NC * NC * 4);

  crf_fwd<<<NB, 1024, 0, stream>>>(pot, trans, out);
  crf_bwd<<<NB, 256, NC * NC * 4, stream>>>(trans, out);
}

// Round 3
// 538.986 us; speedup vs baseline: 1.7554x; 1.0300x over previous
//
#include <hip/hip_runtime.h>

// Viterbi CRF decode: potentials [B,T,C] f32, transitions [C,C] f32 -> one-hot [B,T,C] f32
// B=256, T=1024, C=128.
//
// crf_fwd : max-only DP. 512 threads/block, 1 block/batch/CU.
//           Lane (w, r=l>>4, i=l&15): c-quad g = w*4+r (c in 4g..4g+3), p-chunk i (p in 8i..8i+7).
//           Per step: 2x ds_read_b128 (8 alphas shared across 4 c's), 32 add, 4x tree-max,
//           all-DPP cross-lane reduce (quad_perm halving on lane bits 0,1; row_shr:4/8 fold).
//           Writer lanes i>=12 (one per c) add pot, write LDS double-buffer + stash alpha
//           row to d_out (scratch for bwd). Raw lgkmcnt-only barrier per step.
// crf_bwd : recomputes backpointers from stored alphas (exact fp32 replay -> identical
//           argmax, first-occurrence ties), chases the path, overwrites d_out with one-hot.

constexpr int NB = 256;
constexpr int NT = 1024;
constexpr int NC = 128;

// ---------------- DPP helpers ----------------

template <int CTRL>
__device__ __forceinline__ float dpp_mov(float v) {
  // bound_ctrl=false: out-of-range lanes keep old (= own value) -> max(v,v) harmless
  return __int_as_float(__builtin_amdgcn_update_dpp(
      __float_as_int(v), __float_as_int(v), CTRL, 0xF, 0xF, false));
}

template <int CTRL>
__device__ __forceinline__ float fmax_dpp(float v) {
  return fmaxf(v, dpp_mov<CTRL>(v));
}

// full-wave (64-lane) max reduce, result valid at lane 63
__device__ __forceinline__ float wave_max_to_lane63(float m) {
  m = fmax_dpp<0x111>(m);  // row_shr:1
  m = fmax_dpp<0x112>(m);  // row_shr:2
  m = fmax_dpp<0x114>(m);  // row_shr:4
  m = fmax_dpp<0x118>(m);  // row_shr:8  -> lane15 of each row has row max
  m = fmax_dpp<0x142>(m);  // row_bcast:15
  m = fmax_dpp<0x143>(m);  // row_bcast:31 -> lane63 has full max
  return m;
}

// ---------------- forward ----------------
// alpha LDS layout: p stored at 12*(p>>3) + (p&7); chunk i at floats 12i..12i+7.
// b128 reads at float offsets 12i / 12i+4: 16B-aligned, banks 2-way max (free).

constexpr int ABUF = 192;  // padded floats per buffer (16 chunks * 12)

__global__ __launch_bounds__(512)
void crf_fwd(const float* __restrict__ pot, const float* __restrict__ trans,
             float* __restrict__ out) {
  __shared__ __align__(16) float alpha[2 * ABUF];

  const int tid = threadIdx.x;
  const int b = blockIdx.x;
  const int w = tid >> 6;          // wave 0..7
  const int l = tid & 63;          // lane
  const int r = l >> 4;            // row 0..3
  const int i = l & 15;            // p-chunk
  const int g = w * 4 + r;         // c-quad 0..31
  const bool b0 = (l & 1) != 0;
  const bool b1 = (l & 2) != 0;
  const bool wr = (i >= 12);       // writer lanes: one per c in the quad
  const int cw = 4 * g + 2 * (i & 1) + ((i >> 1) & 1);   // writer's c
  const int widx = 12 * (cw >> 3) + (cw & 7);            // writer's padded LDS index

  const float* potb = pot + (size_t)b * NT * NC;
  float* outb = out + (size_t)b * NT * NC;

  // time-invariant transitions: tr[pp][jj] = trans[8i+pp][4g+jj]
  float tr[8][4];
  #pragma unroll
  for (int pp = 0; pp < 8; ++pp) {
    float4 v = *(const float4*)(trans + (8 * i + pp) * NC + 4 * g);
    tr[pp][0] = v.x; tr[pp][1] = v.y; tr[pp][2] = v.z; tr[pp][3] = v.w;
  }

  float pc[8], pn[8];  // pot row prefetch (writer lanes only)
  if (wr) {
    float a0v = potb[cw];                    // alpha_0 = pot[:,0,:]
    alpha[widx] = a0v;
    outb[cw] = a0v;                          // stash alpha row 0
    #pragma unroll
    for (int j = 0; j < 8; ++j) pc[j] = potb[(1 + j) * NC + cw];
  }
  asm volatile("s_waitcnt lgkmcnt(0)\n\ts_barrier" ::: "memory");

  auto STEP = [&](int t, int j, int CUR) {
    const float4* af = (const float4*)(alpha + CUR * ABUF);
    float4 a0 = af[3 * i];         // p 8i..8i+3
    float4 a1 = af[3 * i + 1];     // p 8i+4..8i+7
    const float av[8] = {a0.x, a0.y, a0.z, a0.w, a1.x, a1.y, a1.z, a1.w};
    float mj[4];
    #pragma unroll
    for (int jj = 0; jj < 4; ++jj) {
      float x0 = fmaxf(av[0] + tr[0][jj], av[1] + tr[1][jj]);
      float x1 = fmaxf(av[2] + tr[2][jj], av[3] + tr[3][jj]);
      float x2 = fmaxf(av[4] + tr[4][jj], av[5] + tr[5][jj]);
      float x3 = fmaxf(av[6] + tr[6][jj], av[7] + tr[7][jj]);
      mj[jj] = fmaxf(fmaxf(x0, x1), fmaxf(x2, x3));
    }
    // ---- all-DPP reduce over the 16 p-chunks ----
    // xor1 halving: keep c-pair by lane bit0
    float t0 = dpp_mov<0xB1>(mj[0]);
    float t1 = dpp_mov<0xB1>(mj[1]);
    float t2 = dpp_mov<0xB1>(mj[2]);
    float t3 = dpp_mov<0xB1>(mj[3]);
    float r0 = fmaxf(b0 ? mj[2] : mj[0], b0 ? t2 : t0);
    float r1 = fmaxf(b0 ? mj[3] : mj[1], b0 ? t3 : t1);
    // xor2 halving: keep single c by lane bit1
    float u0 = dpp_mov<0x4E>(r0);
    float u1 = dpp_mov<0x4E>(r1);
    float q = fmaxf(b1 ? r1 : r0, b1 ? u1 : u0);
    // fold the 4 quads of the row toward high lanes; complete for i>=12
    q = fmaxf(q, dpp_mov<0x114>(q));   // row_shr:4
    q = fmaxf(q, dpp_mov<0x118>(q));   // row_shr:8
    if (wr) {
      float na = q + pc[j];
      alpha[(CUR ^ 1) * ABUF + widx] = na;
      outb[(size_t)t * NC + cw] = na;      // stash alpha row t (fire-and-forget)
    }
    asm volatile("s_waitcnt lgkmcnt(0)\n\ts_barrier" ::: "memory");
  };

  // 1023 steps = 127 groups of 8 + 7 tail; CUR returns to 0 every group
  for (int grp = 0; grp < 127; ++grp) {
    if (wr) {
      #pragma unroll
      for (int j = 0; j < 8; ++j) {
        int row = 9 + 8 * grp + j;
        if (row > NT - 1) row = NT - 1;
        pn[j] = potb[(size_t)row * NC + cw];
      }
    }
    const int t0 = 1 + 8 * grp;
    STEP(t0 + 0, 0, 0); STEP(t0 + 1, 1, 1); STEP(t0 + 2, 2, 0); STEP(t0 + 3, 3, 1);
    STEP(t0 + 4, 4, 0); STEP(t0 + 5, 5, 1); STEP(t0 + 6, 6, 0); STEP(t0 + 7, 7, 1);
    #pragma unroll
    for (int j = 0; j < 8; ++j) pc[j] = pn[j];
  }
  STEP(1017, 0, 0); STEP(1018, 1, 1); STEP(1019, 2, 0); STEP(1020, 3, 1);
  STEP(1021, 4, 0); STEP(1022, 5, 1); STEP(1023, 6, 0);
}

// ---------------- backward ----------------
// 256 threads: all 4 waves transpose trans into LDS, then wave 0 chases the
// path. Lane l owns states p = l and p = 64+l. Alpha rows register-prefetched
// 8 deep (independent of the serial tag chain). One-hot row t overwrites the
// already-consumed alpha row t in place.

__global__ __launch_bounds__(256)
void crf_bwd(const float* __restrict__ trans, float* __restrict__ out) {
  extern __shared__ float tT[];  // [NC][NC] : tT[c][p] = trans[p][c]
  const int tid = threadIdx.x;
  const int b = blockIdx.x;
  float* outb = out + (size_t)b * NT * NC;

  {
    const int r = tid >> 1;   // source row p
    const int h = tid & 1;    // which half of the row
    const float4* src = (const float4*)(trans + r * NC + h * 64);
    #pragma unroll
    for (int j = 0; j < 16; ++j) {
      float4 q = src[j];
      int cb = h * 64 + 4 * j;
      tT[(cb + 0) * NC + r] = q.x;   // bank = r%32: conflict-free across lanes
      tT[(cb + 1) * NC + r] = q.y;
      tT[(cb + 2) * NC + r] = q.z;
      tT[(cb + 3) * NC + r] = q.w;
    }
  }
  __syncthreads();
  if (tid >= 64) return;
  const int l = tid;

  // last_tag = first argmax of alpha[T-1]
  float zlo = outb[(NT - 1) * NC + l];
  float zhi = outb[(NT - 1) * NC + 64 + l];
  float m0 = wave_max_to_lane63(fmaxf(zlo, zhi));
  float M0 = __int_as_float(__builtin_amdgcn_readlane(__float_as_int(m0), 63));
  unsigned long long bl = __ballot(zlo == M0);
  unsigned long long bh = __ballot(zhi == M0);
  int tag = bl ? (__ffsll((long long)bl) - 1)
               : (64 + __ffsll((long long)bh) - 1);

  // prefetch alpha rows 1022..1015
  float clo[8], chi[8], nlo[8], nhi[8];
  #pragma unroll
  for (int j = 0; j < 8; ++j) {
    clo[j] = outb[(NT - 2 - j) * NC + l];
    chi[j] = outb[(NT - 2 - j) * NC + 64 + l];
  }

  for (int g = 0; g < 128; ++g) {
    #pragma unroll
    for (int j = 0; j < 8; ++j) {      // prefetch group g+1 (rows 1014-8g-j)
      int r = NT - 10 - 8 * g - j;
      if (r < 0) r = 0;
      nlo[j] = outb[r * NC + l];
      nhi[j] = outb[r * NC + 64 + l];
    }
    #pragma unroll
    for (int j = 0; j < 8; ++j) {
      int t = NT - 1 - 8 * g - j;
      if (t >= 1) {
        // one-hot for row t (alpha[t] already consumed last iteration)
        outb[t * NC + l]      = (l == tag) ? 1.0f : 0.0f;
        outb[t * NC + 64 + l] = (64 + l == tag) ? 1.0f : 0.0f;
        // bp: first argmax_p( alpha[t-1][p] + trans[p][tag] )
        float lo = clo[j] + tT[tag * NC + l];
        float hi = chi[j] + tT[tag * NC + 64 + l];
        float m = wave_max_to_lane63(fmaxf(lo, hi));
        float M = __int_as_float(__builtin_amdgcn_readlane(__float_as_int(m), 63));
        unsigned long long el = __ballot(lo == M);
        unsigned long long eh = __ballot(hi == M);
        tag = el ? (__ffsll((long long)el) - 1)
                 : (64 + __ffsll((long long)eh) - 1);
      }
    }
    #pragma unroll
    for (int j = 0; j < 8; ++j) { clo[j] = nlo[j]; chi[j] = nhi[j]; }
  }
  outb[l]      = (l == tag) ? 1.0f : 0.0f;
  outb[64 + l] = (64 + l == tag) ? 1.0f : 0.0f;
}

// ---------------- launch ----------------

extern "C" void kernel_launch(void* const* d_in, const int* in_sizes, int n_in,
                              void* d_out, int out_size, void* d_ws, size_t ws_size,
                              hipStream_t stream) {
  const float* pot   = (const float*)d_in[0];
  const float* trans = (const float*)d_in[1];
  float* out = (float*)d_out;

  hipFuncSetAttribute((const void*)crf_bwd,
                      hipFuncAttributeMaxDynamicSharedMemorySize, NC * NC * 4);

  crf_fwd<<<NB, 512, 0, stream>>>(pot, trans, out);
  crf_bwd<<<NB, 256, NC * NC * 4, stream>>>(trans, out);
}

// Round 4
// 493.995 us; speedup vs baseline: 1.9153x; 1.0911x over previous
//
#include <hip/hip_runtime.h>

// Viterbi CRF decode: potentials [B,T,C] f32, transitions [C,C] f32 -> one-hot [B,T,C] f32
// B=256, T=1024, C=128.
//
// crf_fwd : max-only DP (no argmax). Stashes q_t = max_p(alpha_{t-1}[p]+T[p][c])
//           (PRE-pot max) rows into d_out as scratch; row 0 = zeros (so
//           alpha_0 = 0 + pot_0 exactly). LDS alpha double-buffer carries
//           alpha_t = q_t + pot_t.
// crf_bwd : per step t: M = q_t[tag] (exact max, via readlane) ->
//           backpointer = first p with (q_{t-1}[p]+pot_{t-1}[p]) + T[p][tag] == M
//           (bit-identical replay of fwd's adds) -> ballot+ffs. No max-reduce.
//           Overwrites d_out with the one-hot decode.

typedef float f32x2 __attribute__((ext_vector_type(2)));

constexpr int NB = 256;
constexpr int NT = 1024;
constexpr int NC = 128;

// ---------------- DPP helpers ----------------

template <int CTRL>
__device__ __forceinline__ float dpp_mov(float v) {
  return __int_as_float(__builtin_amdgcn_update_dpp(
      __float_as_int(v), __float_as_int(v), CTRL, 0xF, 0xF, false));
}

template <int CTRL>
__device__ __forceinline__ float fmax_dpp(float v) {
  return fmaxf(v, dpp_mov<CTRL>(v));
}

__device__ __forceinline__ float wave_max_to_lane63(float m) {
  m = fmax_dpp<0x111>(m);  // row_shr:1
  m = fmax_dpp<0x112>(m);  // row_shr:2
  m = fmax_dpp<0x114>(m);  // row_shr:4
  m = fmax_dpp<0x118>(m);  // row_shr:8
  m = fmax_dpp<0x142>(m);  // row_bcast:15
  m = fmax_dpp<0x143>(m);  // row_bcast:31 -> lane63 has full max
  return m;
}

// ---------------- forward ----------------
// alpha LDS layout: p stored at 12*(p>>3) + (p&7); chunk i at floats 12i..12i+7.

constexpr int ABUF = 192;  // padded floats per buffer (16 chunks * 12)

__global__ __launch_bounds__(512, 2)
void crf_fwd(const float* __restrict__ pot, const float* __restrict__ trans,
             float* __restrict__ out) {
  __shared__ __align__(16) float alpha[2 * ABUF];

  const int tid = threadIdx.x;
  const int b = blockIdx.x;
  const int w = tid >> 6;          // wave 0..7
  const int l = tid & 63;          // lane
  const int r = l >> 4;            // row 0..3
  const int i = l & 15;            // p-chunk
  const int g = w * 4 + r;         // c-quad 0..31
  const bool b0 = (l & 1) != 0;
  const bool b1 = (l & 2) != 0;
  const bool wr = (i >= 12);       // writer lanes: one per c in the quad
  const int cw = 4 * g + 2 * (i & 1) + ((i >> 1) & 1);   // writer's c
  const int widx = 12 * (cw >> 3) + (cw & 7);            // writer's padded LDS index

  const float* potb = pot + (size_t)b * NT * NC;
  float* outb = out + (size_t)b * NT * NC;

  // time-invariant transitions, packed along p: tr2[k][jj] = (T[8i+2k][4g+jj], T[8i+2k+1][4g+jj])
  f32x2 tr2[4][4];
  #pragma unroll
  for (int k = 0; k < 4; ++k) {
    float4 e = *(const float4*)(trans + (8 * i + 2 * k) * NC + 4 * g);
    float4 o = *(const float4*)(trans + (8 * i + 2 * k + 1) * NC + 4 * g);
    tr2[k][0] = f32x2{e.x, o.x}; tr2[k][1] = f32x2{e.y, o.y};
    tr2[k][2] = f32x2{e.z, o.z}; tr2[k][3] = f32x2{e.w, o.w};
  }

  float pc[8], pn[8];  // pot row prefetch (writer lanes only)
  if (wr) {
    alpha[widx] = potb[cw];                  // alpha_0 = pot[:,0,:]
    outb[cw] = 0.0f;                         // q_0 := 0  (alpha_0 = 0 + pot_0)
    #pragma unroll
    for (int j = 0; j < 8; ++j) pc[j] = potb[(1 + j) * NC + cw];
  }
  asm volatile("s_waitcnt lgkmcnt(0)\n\ts_barrier" ::: "memory");

  auto STEP = [&](int t, int j, int CUR) {
    const float4* af = (const float4*)(alpha + CUR * ABUF);
    float4 a0 = af[3 * i];         // p 8i..8i+3
    float4 a1 = af[3 * i + 1];     // p 8i+4..8i+7
    f32x2 av[4] = {f32x2{a0.x, a0.y}, f32x2{a0.z, a0.w},
                   f32x2{a1.x, a1.y}, f32x2{a1.z, a1.w}};
    float mj[4];
    #pragma unroll
    for (int jj = 0; jj < 4; ++jj) {
      f32x2 s0 = av[0] + tr2[0][jj];   // v_pk_add_f32
      f32x2 s1 = av[1] + tr2[1][jj];
      f32x2 s2 = av[2] + tr2[2][jj];
      f32x2 s3 = av[3] + tr2[3][jj];
      mj[jj] = fmaxf(fmaxf(fmaxf(s0.x, s0.y), fmaxf(s1.x, s1.y)),
                     fmaxf(fmaxf(s2.x, s2.y), fmaxf(s3.x, s3.y)));
    }
    // ---- all-DPP reduce over the 16 p-chunks (identical to r3) ----
    float t0 = dpp_mov<0xB1>(mj[0]);
    float t1 = dpp_mov<0xB1>(mj[1]);
    float t2 = dpp_mov<0xB1>(mj[2]);
    float t3 = dpp_mov<0xB1>(mj[3]);
    float r0 = fmaxf(b0 ? mj[2] : mj[0], b0 ? t2 : t0);
    float r1 = fmaxf(b0 ? mj[3] : mj[1], b0 ? t3 : t1);
    float u0 = dpp_mov<0x4E>(r0);
    float u1 = dpp_mov<0x4E>(r1);
    float q = fmaxf(b1 ? r1 : r0, b1 ? u1 : u0);
    q = fmaxf(q, dpp_mov<0x114>(q));   // row_shr:4
    q = fmaxf(q, dpp_mov<0x118>(q));   // row_shr:8
    if (wr) {
      alpha[(CUR ^ 1) * ABUF + widx] = q + pc[j];   // alpha_t into LDS
      outb[(size_t)t * NC + cw] = q;                // stash PRE-pot max q_t
    }
    asm volatile("s_waitcnt lgkmcnt(0)\n\ts_barrier" ::: "memory");
  };

  for (int grp = 0; grp < 127; ++grp) {
    if (wr) {
      #pragma unroll
      for (int j = 0; j < 8; ++j) {
        int row = 9 + 8 * grp + j;
        if (row > NT - 1) row = NT - 1;
        pn[j] = potb[(size_t)row * NC + cw];
      }
    }
    const int t0s = 1 + 8 * grp;
    STEP(t0s + 0, 0, 0); STEP(t0s + 1, 1, 1); STEP(t0s + 2, 2, 0); STEP(t0s + 3, 3, 1);
    STEP(t0s + 4, 4, 0); STEP(t0s + 5, 5, 1); STEP(t0s + 6, 6, 0); STEP(t0s + 7, 7, 1);
    #pragma unroll
    for (int j = 0; j < 8; ++j) pc[j] = pn[j];
  }
  STEP(1017, 0, 0); STEP(1018, 1, 1); STEP(1019, 2, 0); STEP(1020, 3, 1);
  STEP(1021, 4, 0); STEP(1022, 5, 1); STEP(1023, 6, 0);
}

// ---------------- backward ----------------
// tTp[c][l] = (T[l][c], T[64+l][c]) as float2 in LDS (64 KiB).
// Wave 0 chases; per step only an equality scan against M = q_t[tag].

__global__ __launch_bounds__(256)
void crf_bwd(const float* __restrict__ pot, const float* __restrict__ trans,
             float* __restrict__ out) {
  extern __shared__ float tTf[];   // float2[NC][64] interleaved
  const int tid = threadIdx.x;
  const int b = blockIdx.x;
  const float* potb = pot + (size_t)b * NT * NC;
  float* outb = out + (size_t)b * NT * NC;

  {
    const int rr = tid >> 1;   // source row p of trans
    const int h = tid & 1;     // which half of the row
    const float4* src = (const float4*)(trans + rr * NC + h * 64);
    const int lo = rr & 63, hb = rr >> 6;
    #pragma unroll
    for (int j = 0; j < 16; ++j) {
      float4 q = src[j];
      int cb = h * 64 + 4 * j;
      tTf[(cb + 0) * 128 + lo * 2 + hb] = q.x;
      tTf[(cb + 1) * 128 + lo * 2 + hb] = q.y;
      tTf[(cb + 2) * 128 + lo * 2 + hb] = q.z;
      tTf[(cb + 3) * 128 + lo * 2 + hb] = q.w;
    }
  }
  __syncthreads();
  if (tid >= 64) return;
  const int l = tid;
  const f32x2* tTp = (const f32x2*)tTf;

  // ---- init at t = NT-1: alpha_last = q_last + pot_last; full argmax (once) ----
  float qlo_t = outb[(NT - 1) * NC + l];
  float qhi_t = outb[(NT - 1) * NC + 64 + l];
  float alo_t = qlo_t + potb[(NT - 1) * NC + l];
  float ahi_t = qhi_t + potb[(NT - 1) * NC + 64 + l];
  float m0 = wave_max_to_lane63(fmaxf(alo_t, ahi_t));
  float M0 = __int_as_float(__builtin_amdgcn_readlane(__float_as_int(m0), 63));
  unsigned long long bl = __ballot(alo_t == M0);
  unsigned long long bh = __ballot(ahi_t == M0);
  int tag = bl ? (__ffsll((long long)bl) - 1)
               : (64 + __ffsll((long long)bh) - 1);

  // ---- prefetch rows 1022..1015 (q and pot), precompute alpha ----
  float cqlo[8], cqhi[8], calo[8], cahi[8];
  float nqlo[8], nqhi[8], nplo[8], nphi[8];
  #pragma unroll
  for (int j = 0; j < 8; ++j) {
    int rw = NT - 2 - j;
    cqlo[j] = outb[rw * NC + l];
    cqhi[j] = outb[rw * NC + 64 + l];
    calo[j] = cqlo[j] + potb[rw * NC + l];
    cahi[j] = cqhi[j] + potb[rw * NC + 64 + l];
  }

  for (int g = 0; g < 128; ++g) {
    #pragma unroll
    for (int j = 0; j < 8; ++j) {      // prefetch group g+1 (rows 1014-8g-j)
      int rw = NT - 10 - 8 * g - j;
      if (rw < 0) rw = 0;
      nqlo[j] = outb[rw * NC + l];
      nqhi[j] = outb[rw * NC + 64 + l];
      nplo[j] = potb[rw * NC + l];
      nphi[j] = potb[rw * NC + 64 + l];
    }
    #pragma unroll
    for (int j = 0; j < 8; ++j) {
      int t = NT - 1 - 8 * g - j;
      if (t >= 1) {
        // one-hot for row t
        outb[t * NC + l]      = (l == tag) ? 1.0f : 0.0f;
        outb[t * NC + 64 + l] = (64 + l == tag) ? 1.0f : 0.0f;
        // exact max of step t, no reduce needed:
        int Mlo = __builtin_amdgcn_readlane(__float_as_int(qlo_t), tag & 63);
        int Mhi = __builtin_amdgcn_readlane(__float_as_int(qhi_t), tag & 63);
        float M = __int_as_float((tag < 64) ? Mlo : Mhi);
        // bp: first p with alpha_{t-1}[p] + T[p][tag] == M
        f32x2 tt = tTp[tag * 64 + l];          // ds_read_b64
        float vlo = calo[j] + tt.x;
        float vhi = cahi[j] + tt.y;
        unsigned long long el = __ballot(vlo == M);
        unsigned long long eh = __ballot(vhi == M);
        tag = el ? (__ffsll((long long)el) - 1)
                 : (64 + __ffsll((long long)eh) - 1);
        qlo_t = cqlo[j];   // row t-1 becomes next step's row t
        qhi_t = cqhi[j];
      }
    }
    #pragma unroll
    for (int j = 0; j < 8; ++j) {
      cqlo[j] = nqlo[j]; cqhi[j] = nqhi[j];
      calo[j] = nqlo[j] + nplo[j];
      cahi[j] = nqhi[j] + nphi[j];
    }
  }
  outb[l]      = (l == tag) ? 1.0f : 0.0f;
  outb[64 + l] = (64 + l == tag) ? 1.0f : 0.0f;
}

// ---------------- launch ----------------

extern "C" void kernel_launch(void* const* d_in, const int* in_sizes, int n_in,
                              void* d_out, int out_size, void* d_ws, size_t ws_size,
                              hipStream_t stream) {
  const float* pot   = (const float*)d_in[0];
  const float* trans = (const float*)d_in[1];
  float* out = (float*)d_out;

  hipFuncSetAttribute((const void*)crf_bwd,
                      hipFuncAttributeMaxDynamicSharedMemorySize, NC * NC * 4);

  crf_fwd<<<NB, 512, 0, stream>>>(pot, trans, out);
  crf_bwd<<<NB, 256, NC * NC * 4, stream>>>(pot, trans, out);
}

// Round 5
// 485.902 us; speedup vs baseline: 1.9472x; 1.0167x over previous
//
#include <hip/hip_runtime.h>

// Viterbi CRF decode: potentials [B,T,C] f32, transitions [C,C] f32 -> one-hot [B,T,C] f32
// B=256, T=1024, C=128.
//
// crf_fwd : max-only DP (no argmax). Stashes q_t = max_p(alpha_{t-1}[p]+T[p][c])
//           (PRE-pot max) rows into d_out as scratch; row 0 = zeros (so
//           alpha_0 = 0 + pot_0 exactly). LDS alpha double-buffer carries
//           alpha_t = q_t + pot_t.
//           KEY r5 fix: asm keep-alives pin the 32-float trans slice in VGPRs
//           (r4's compiler sank those loads into the loop: VGPR_Count=40 proved
//           the "register-resident" transitions were re-fetched every step).
// crf_bwd : per step t: M = q_t[tag] (exact max, via readlane) ->
//           backpointer = first p with (q_{t-1}[p]+pot_{t-1}[p]) + T[p][tag] == M
//           (bit-identical replay of fwd's adds) -> ballot+ffs. No max-reduce.

typedef float f32x2 __attribute__((ext_vector_type(2)));

constexpr int NB = 256;
constexpr int NT = 1024;
constexpr int NC = 128;

// ---------------- helpers ----------------

template <int CTRL>
__device__ __forceinline__ float dpp_mov(float v) {
  return __int_as_float(__builtin_amdgcn_update_dpp(
      __float_as_int(v), __float_as_int(v), CTRL, 0xF, 0xF, false));
}

template <int CTRL>
__device__ __forceinline__ float fmax_dpp(float v) {
  return fmaxf(v, dpp_mov<CTRL>(v));
}

__device__ __forceinline__ float wave_max_to_lane63(float m) {
  m = fmax_dpp<0x111>(m);  // row_shr:1
  m = fmax_dpp<0x112>(m);  // row_shr:2
  m = fmax_dpp<0x114>(m);  // row_shr:4
  m = fmax_dpp<0x118>(m);  // row_shr:8
  m = fmax_dpp<0x142>(m);  // row_bcast:15
  m = fmax_dpp<0x143>(m);  // row_bcast:31 -> lane63 has full max
  return m;
}

// exact 3-input max (max is associative; order-free for the VALUE)
__device__ __forceinline__ float max3f(float a, float b, float c) {
  float d;
  asm("v_max3_f32 %0, %1, %2, %3" : "=v"(d) : "v"(a), "v"(b), "v"(c));
  return d;
}

// ---------------- forward ----------------
// alpha LDS layout: p stored at 12*(p>>3) + (p&7); chunk i at floats 12i..12i+7.

constexpr int ABUF = 192;  // padded floats per buffer (16 chunks * 12)

__global__ __launch_bounds__(512, 2)
void crf_fwd(const float* __restrict__ pot, const float* __restrict__ trans,
             float* __restrict__ out) {
  __shared__ __align__(16) float alpha[2 * ABUF];

  const int tid = threadIdx.x;
  const int b = blockIdx.x;
  const int w = tid >> 6;          // wave 0..7
  const int l = tid & 63;          // lane
  const int r = l >> 4;            // row 0..3
  const int i = l & 15;            // p-chunk
  const int g = w * 4 + r;         // c-quad 0..31
  const bool b0 = (l & 1) != 0;
  const bool b1 = (l & 2) != 0;
  const bool wr = (i >= 12);       // writer lanes: one per c in the quad
  const int cw = 4 * g + 2 * (i & 1) + ((i >> 1) & 1);   // writer's c
  const int widx = 12 * (cw >> 3) + (cw & 7);            // writer's padded LDS index

  const float* potb = pot + (size_t)b * NT * NC;
  float* outb = out + (size_t)b * NT * NC;

  // time-invariant transitions, packed along p: tr2[k][jj] = (T[8i+2k][4g+jj], T[8i+2k+1][4g+jj])
  f32x2 tr2[4][4];
  #pragma unroll
  for (int k = 0; k < 4; ++k) {
    float4 e = *(const float4*)(trans + (8 * i + 2 * k) * NC + 4 * g);
    float4 o = *(const float4*)(trans + (8 * i + 2 * k + 1) * NC + 4 * g);
    tr2[k][0] = f32x2{e.x, o.x}; tr2[k][1] = f32x2{e.y, o.y};
    tr2[k][2] = f32x2{e.z, o.z}; tr2[k][3] = f32x2{e.w, o.w};
  }
  // Pin tr2 in VGPRs: opaque to the compiler -> cannot sink/remat the loads
  // into the 1023-step loop (r4's VGPR_Count=40 showed it was doing exactly that).
  #pragma unroll
  for (int k = 0; k < 4; ++k) {
    #pragma unroll
    for (int jj = 0; jj < 4; ++jj) {
      float x = tr2[k][jj].x, y = tr2[k][jj].y;
      asm volatile("" : "+v"(x), "+v"(y));
      tr2[k][jj] = f32x2{x, y};
    }
  }

  float pc[8], pn[8];  // pot row prefetch (writer lanes only)
  if (wr) {
    alpha[widx] = potb[cw];                  // alpha_0 = pot[:,0,:]
    outb[cw] = 0.0f;                         // q_0 := 0  (alpha_0 = 0 + pot_0)
    #pragma unroll
    for (int j = 0; j < 8; ++j) pc[j] = potb[(1 + j) * NC + cw];
  }
  asm volatile("s_waitcnt lgkmcnt(0)\n\ts_barrier" ::: "memory");

  // per-buffer b128 base pointers (immediate offsets handle the rest)
  const float4* afA = (const float4*)(alpha) + 3 * i;
  const float4* afB = (const float4*)(alpha + ABUF) + 3 * i;

  auto STEP = [&](float* outg, int j, int CUR) {
    const float4* af = CUR ? afB : afA;
    float4 a0 = af[0];             // p 8i..8i+3
    float4 a1 = af[1];             // p 8i+4..8i+7
    f32x2 av[4] = {f32x2{a0.x, a0.y}, f32x2{a0.z, a0.w},
                   f32x2{a1.x, a1.y}, f32x2{a1.z, a1.w}};
    float mj[4];
    #pragma unroll
    for (int jj = 0; jj < 4; ++jj) {
      f32x2 s0 = av[0] + tr2[0][jj];   // v_pk_add_f32
      f32x2 s1 = av[1] + tr2[1][jj];
      f32x2 s2 = av[2] + tr2[2][jj];
      f32x2 s3 = av[3] + tr2[3][jj];
      float t1 = max3f(s0.x, s0.y, s1.x);
      float t2 = max3f(s1.y, s2.x, s2.y);
      float t3 = fmaxf(s3.x, s3.y);
      mj[jj] = max3f(t1, t2, t3);
    }
    // ---- all-DPP reduce over the 16 p-chunks ----
    float t0 = dpp_mov<0xB1>(mj[0]);
    float t1 = dpp_mov<0xB1>(mj[1]);
    float t2 = dpp_mov<0xB1>(mj[2]);
    float t3 = dpp_mov<0xB1>(mj[3]);
    float r0 = fmaxf(b0 ? mj[2] : mj[0], b0 ? t2 : t0);
    float r1 = fmaxf(b0 ? mj[3] : mj[1], b0 ? t3 : t1);
    float u0 = dpp_mov<0x4E>(r0);
    float u1 = dpp_mov<0x4E>(r1);
    float q = fmaxf(b1 ? r1 : r0, b1 ? u1 : u0);
    q = fmaxf(q, dpp_mov<0x114>(q));   // row_shr:4
    q = fmaxf(q, dpp_mov<0x118>(q));   // row_shr:8
    if (wr) {
      alpha[(CUR ^ 1) * ABUF + widx] = q + pc[j];   // alpha_t into LDS
      outg[j * NC] = q;                             // stash PRE-pot max q_t
    }
    asm volatile("s_waitcnt lgkmcnt(0)\n\ts_barrier" ::: "memory");
  };

  for (int grp = 0; grp < 127; ++grp) {
    if (wr) {
      #pragma unroll
      for (int j = 0; j < 8; ++j) {
        int row = 9 + 8 * grp + j;
        if (row > NT - 1) row = NT - 1;
        pn[j] = potb[(size_t)row * NC + cw];
      }
    }
    float* outg = outb + (size_t)(1 + 8 * grp) * NC + cw;
    STEP(outg, 0, 0); STEP(outg, 1, 1); STEP(outg, 2, 0); STEP(outg, 3, 1);
    STEP(outg, 4, 0); STEP(outg, 5, 1); STEP(outg, 6, 0); STEP(outg, 7, 1);
    #pragma unroll
    for (int j = 0; j < 8; ++j) pc[j] = pn[j];
  }
  {
    float* outg = outb + (size_t)1017 * NC + cw;
    STEP(outg, 0, 0); STEP(outg, 1, 1); STEP(outg, 2, 0); STEP(outg, 3, 1);
    STEP(outg, 4, 0); STEP(outg, 5, 1); STEP(outg, 6, 0);
  }
}

// ---------------- backward ----------------
// tTp[c][l] = (T[l][c], T[64+l][c]) as float2 in LDS (64 KiB).
// Wave 0 chases; per step only an equality scan against M = q_t[tag].

__global__ __launch_bounds__(256)
void crf_bwd(const float* __restrict__ pot, const float* __restrict__ trans,
             float* __restrict__ out) {
  extern __shared__ float tTf[];   // float2[NC][64] interleaved
  const int tid = threadIdx.x;
  const int b = blockIdx.x;
  const float* potb = pot + (size_t)b * NT * NC;
  float* outb = out + (size_t)b * NT * NC;

  {
    const int rr = tid >> 1;   // source row p of trans
    const int h = tid & 1;     // which half of the row
    const float4* src = (const float4*)(trans + rr * NC + h * 64);
    const int lo = rr & 63, hb = rr >> 6;
    #pragma unroll
    for (int j = 0; j < 16; ++j) {
      float4 q = src[j];
      int cb = h * 64 + 4 * j;
      tTf[(cb + 0) * 128 + lo * 2 + hb] = q.x;
      tTf[(cb + 1) * 128 + lo * 2 + hb] = q.y;
      tTf[(cb + 2) * 128 + lo * 2 + hb] = q.z;
      tTf[(cb + 3) * 128 + lo * 2 + hb] = q.w;
    }
  }
  __syncthreads();
  if (tid >= 64) return;
  const int l = tid;
  const f32x2* tTp = (const f32x2*)tTf;

  // ---- init at t = NT-1: alpha_last = q_last + pot_last; full argmax (once) ----
  float qlo_t = outb[(NT - 1) * NC + l];
  float qhi_t = outb[(NT - 1) * NC + 64 + l];
  float alo_t = qlo_t + potb[(NT - 1) * NC + l];
  float ahi_t = qhi_t + potb[(NT - 1) * NC + 64 + l];
  float m0 = wave_max_to_lane63(fmaxf(alo_t, ahi_t));
  float M0 = __int_as_float(__builtin_amdgcn_readlane(__float_as_int(m0), 63));
  unsigned long long bl = __ballot(alo_t == M0);
  unsigned long long bh = __ballot(ahi_t == M0);
  int tag = bl ? (__ffsll((long long)bl) - 1)
               : (64 + __ffsll((long long)bh) - 1);

  // ---- prefetch rows 1022..1015 (q and pot), precompute alpha ----
  float cqlo[8], cqhi[8], calo[8], cahi[8];
  float nqlo[8], nqhi[8], nplo[8], nphi[8];
  #pragma unroll
  for (int j = 0; j < 8; ++j) {
    int rw = NT - 2 - j;
    cqlo[j] = outb[rw * NC + l];
    cqhi[j] = outb[rw * NC + 64 + l];
    calo[j] = cqlo[j] + potb[rw * NC + l];
    cahi[j] = cqhi[j] + potb[rw * NC + 64 + l];
  }

  for (int g = 0; g < 128; ++g) {
    #pragma unroll
    for (int j = 0; j < 8; ++j) {      // prefetch group g+1 (rows 1014-8g-j)
      int rw = NT - 10 - 8 * g - j;
      if (rw < 0) rw = 0;
      nqlo[j] = outb[rw * NC + l];
      nqhi[j] = outb[rw * NC + 64 + l];
      nplo[j] = potb[rw * NC + l];
      nphi[j] = potb[rw * NC + 64 + l];
    }
    #pragma unroll
    for (int j = 0; j < 8; ++j) {
      int t = NT - 1 - 8 * g - j;
      if (t >= 1) {
        // one-hot for row t
        outb[t * NC + l]      = (l == tag) ? 1.0f : 0.0f;
        outb[t * NC + 64 + l] = (64 + l == tag) ? 1.0f : 0.0f;
        // exact max of step t, no reduce needed:
        int Mlo = __builtin_amdgcn_readlane(__float_as_int(qlo_t), tag & 63);
        int Mhi = __builtin_amdgcn_readlane(__float_as_int(qhi_t), tag & 63);
        float M = __int_as_float((tag < 64) ? Mlo : Mhi);
        // bp: first p with alpha_{t-1}[p] + T[p][tag] == M
        f32x2 tt = tTp[tag * 64 + l];          // ds_read_b64
        float vlo = calo[j] + tt.x;
        float vhi = cahi[j] + tt.y;
        unsigned long long el = __ballot(vlo == M);
        unsigned long long eh = __ballot(vhi == M);
        tag = el ? (__ffsll((long long)el) - 1)
                 : (64 + __ffsll((long long)eh) - 1);
        qlo_t = cqlo[j];   // row t-1 becomes next step's row t
        qhi_t = cqhi[j];
      }
    }
    #pragma unroll
    for (int j = 0; j < 8; ++j) {
      cqlo[j] = nqlo[j]; cqhi[j] = nqhi[j];
      calo[j] = nqlo[j] + nplo[j];
      cahi[j] = nqhi[j] + nphi[j];
    }
  }
  outb[l]      = (l == tag) ? 1.0f : 0.0f;
  outb[64 + l] = (64 + l == tag) ? 1.0f : 0.0f;
}

// ---------------- launch ----------------

extern "C" void kernel_launch(void* const* d_in, const int* in_sizes, int n_in,
                              void* d_out, int out_size, void* d_ws, size_t ws_size,
                              hipStream_t stream) {
  const float* pot   = (const float*)d_in[0];
  const float* trans = (const float*)d_in[1];
  float* out = (float*)d_out;

  hipFuncSetAttribute((const void*)crf_bwd,
                      hipFuncAttributeMaxDynamicSharedMemorySize, NC * NC * 4);

  crf_fwd<<<NB, 512, 0, stream>>>(pot, trans, out);
  crf_bwd<<<NB, 256, NC * NC * 4, stream>>>(pot, trans, out);
}